// Round 5
// baseline (2362.893 us; speedup 1.0000x reference)
//
#include <hip/hip_runtime.h>

// VQ: B=200000 rows (D=128 fp32) vs K=1024 codes; out = [quant B*D | codes B] fp32.
//
// R7 (building on R6, which proved the MFMA+margin+exact-recheck approach at
// absmax 0.0 but mis-sized both halves):
//  * Main GEMM: 2-term split dot ~ Xh.Ch + (Xl*2048).Ch / 2048 -- the SAME
//    fp16 B-fragment (Ch) feeds both accumulators, so K_eff=256 costs zero
//    extra B traffic. B2 = 256 KB hi-frags, L2-resident.
//  * rows=64/wave (was 16): per-wave B2 stream amortized 4x ->
//    L2 traffic 9.8 GB -> 1.6 GB. Block = 1 wave, no LDS in the hot loop,
//    no barriers.
//  * Scaling lo-parts by 2048 kills the fp16-denorm-flush error term:
//    rigorous E_dot <= 5.7e-4*sum|x| + 0.008 -> thr = 2.4e-3*sax + 0.04.
//    Rows with (best2-best1) < thr get exact recheck; others provably match
//    the exact-chain argmin.
//  * recheck v2: one wave handles EIGHT flagged rows (codebook 512KB read
//    amortized 8x -- R6 read it per-row) and the grid is 2048 blocks
//    grid-strided (R6's fixed 1024 waves gave 8% VALUBusy).
// Numerics: recheck reproduces the R2..R5 exact serial-fma chain + 4-chain
// xsq + fmaf(-2,dot,xsq)+csq + ascending-index tie-breaks; unflagged rows are
// provably identical -> absmax 0.0.

typedef _Float16 f16;
typedef f16 h8 __attribute__((ext_vector_type(8)));
typedef float f4 __attribute__((ext_vector_type(4)));

#define DDIM 128
#define KCODES 1024

// ---------------- csq (exact 4-chain) + zero flag counter --------------------
__global__ void csq_kernel(const float* __restrict__ cb, float* __restrict__ csq,
                           int* __restrict__ cnt) {
    if (blockIdx.x == 0 && threadIdx.x == 0) *cnt = 0;
    int k = blockIdx.x * blockDim.x + threadIdx.x;
    if (k >= KCODES) return;
    const float* __restrict__ c = cb + (long)k * DDIM;
    float s0 = 0.f, s1 = 0.f, s2 = 0.f, s3 = 0.f;
#pragma unroll
    for (int d = 0; d < DDIM; d += 4) {
        s0 = fmaf(c[d + 0], c[d + 0], s0);
        s1 = fmaf(c[d + 1], c[d + 1], s1);
        s2 = fmaf(c[d + 2], c[d + 2], s2);
        s3 = fmaf(c[d + 3], c[d + 3], s3);
    }
    csq[k] = (s0 + s1) + (s2 + s3);
}

// ---------------- pack Ch frag-linear (256 KB) -------------------------------
// tile = c16*4 + kf; lane supplies col = c16*16 + (l&15), k = kf*32+(l>>4)*8+j.
// Same (lane,j)->k convention as the A frags (permutation-cancel insurance,
// validated by R6's absmax 0.0).
__global__ void bprep_kernel(const float* __restrict__ cb, h8* __restrict__ B2) {
    const int t = blockIdx.x * 256 + threadIdx.x;   // 0..16383
    const int tile = t >> 6;                        // 0..255
    const int lane = t & 63;
    const int c16 = tile >> 2, kf = tile & 3;
    const int col = c16 * 16 + (lane & 15);
    const int k0 = kf * 32 + (lane >> 4) * 8;
    const float* __restrict__ p = cb + (long)col * DDIM + k0;
    h8 out;
#pragma unroll
    for (int j = 0; j < 8; ++j) out[j] = (f16)p[j];
    B2[tile * 64 + lane] = out;
}

// ---------------- main MFMA kernel: 1 wave = 64 rows x 1024 codes ------------
__launch_bounds__(64, 2)
__global__ void vq_mfma_kernel(const float* __restrict__ x, const float* __restrict__ cb,
                               const h8* __restrict__ B2, const float* __restrict__ csq,
                               float* __restrict__ quant, float* __restrict__ codes,
                               int* __restrict__ cnt, int* __restrict__ list) {
    __shared__ int win[64];
    const int lane = threadIdx.x;
    const long gr0 = (long)blockIdx.x * 64;
    const int lr = lane & 15;     // A-row / B-col within a frag
    const int lk = lane >> 4;     // k-group

    // ---- A frags: hi = fp16(x), lo = fp16((x - hi)*2048); per-row sum|x| ----
    h8 ah[4][4], al[4][4];
    float sax[4];
#pragma unroll
    for (int rf = 0; rf < 4; ++rf) {
        float sx = 0.f;
#pragma unroll
        for (int kf = 0; kf < 4; ++kf) {
            const float* __restrict__ p =
                x + (gr0 + rf * 16 + lr) * DDIM + kf * 32 + lk * 8;
            const float4 u0 = *(const float4*)p;
            const float4 u1 = *(const float4*)(p + 4);
            const float xv[8] = {u0.x, u0.y, u0.z, u0.w, u1.x, u1.y, u1.z, u1.w};
#pragma unroll
            for (int j = 0; j < 8; ++j) {
                const float v = xv[j];
                const f16 h = (f16)v;
                ah[rf][kf][j] = h;
                al[rf][kf][j] = (f16)((v - (float)h) * 2048.f);
                sx += fabsf(v);
            }
        }
        sx += __shfl_xor(sx, 16);
        sx += __shfl_xor(sx, 32);
        sax[rf] = sx;   // full-row sum|x| of row rf*16+lr, same at all lanes
    }

    float b1[16], b2[16];
    int ic[16];   // winning c16 block per slot (col reconstructed later)
#pragma unroll
    for (int t = 0; t < 16; ++t) { b1[t] = 3.4e38f; b2[t] = 3.4e38f; ic[t] = 0; }

    const h8* __restrict__ bp = B2 + lane;
#pragma unroll 1
    for (int c16 = 0; c16 < 64; ++c16) {
        const h8 bf0 = bp[(c16 * 4 + 0) * 64];
        const h8 bf1 = bp[(c16 * 4 + 1) * 64];
        const h8 bf2 = bp[(c16 * 4 + 2) * 64];
        const h8 bf3 = bp[(c16 * 4 + 3) * 64];
        const float cq = csq[c16 * 16 + lr];
#pragma unroll
        for (int rf = 0; rf < 4; ++rf) {
            f4 hi = (f4){0.f, 0.f, 0.f, 0.f};
            f4 mid = (f4){0.f, 0.f, 0.f, 0.f};
            hi  = __builtin_amdgcn_mfma_f32_16x16x32_f16(ah[rf][0], bf0, hi, 0, 0, 0);
            mid = __builtin_amdgcn_mfma_f32_16x16x32_f16(al[rf][0], bf0, mid, 0, 0, 0);
            hi  = __builtin_amdgcn_mfma_f32_16x16x32_f16(ah[rf][1], bf1, hi, 0, 0, 0);
            mid = __builtin_amdgcn_mfma_f32_16x16x32_f16(al[rf][1], bf1, mid, 0, 0, 0);
            hi  = __builtin_amdgcn_mfma_f32_16x16x32_f16(ah[rf][2], bf2, hi, 0, 0, 0);
            mid = __builtin_amdgcn_mfma_f32_16x16x32_f16(al[rf][2], bf2, mid, 0, 0, 0);
            hi  = __builtin_amdgcn_mfma_f32_16x16x32_f16(ah[rf][3], bf3, hi, 0, 0, 0);
            mid = __builtin_amdgcn_mfma_f32_16x16x32_f16(al[rf][3], bf3, mid, 0, 0, 0);
            // score = csq - 2*dot (xsq is per-row constant -> argmin-invariant)
#pragma unroll
            for (int r = 0; r < 4; ++r) {
                const float dot = fmaf(mid[r], 4.8828125e-4f, hi[r]);  // /2048
                const float s = fmaf(-2.0f, dot, cq);
                const int t = rf * 4 + r;
                b2[t] = fminf(fmaxf(s, b1[t]), b2[t]);   // med3 second-best
                if (s < b1[t]) { b1[t] = s; ic[t] = c16; }
            }
        }
    }

    // ---- full col index; reduce (b1,i1,b2) across the 16 lr-lanes ----
    int i1[16];
#pragma unroll
    for (int t = 0; t < 16; ++t) i1[t] = ic[t] * 16 + lr;
#pragma unroll
    for (int t = 0; t < 16; ++t) {
#pragma unroll
        for (int off = 1; off <= 8; off <<= 1) {
            const float ob1 = __shfl_xor(b1[t], off);
            const int   oi  = __shfl_xor(i1[t], off);
            const float ob2 = __shfl_xor(b2[t], off);
            const bool ow = (ob1 < b1[t]) || (ob1 == b1[t] && oi < i1[t]);
            const float nb2 = ow ? fminf(b1[t], ob2) : fminf(ob1, b2[t]);
            if (ow) { b1[t] = ob1; i1[t] = oi; }
            b2[t] = nb2;
        }
    }

    // thresholds per (rf,r): row rf*16 + lk*4 + r (shfl done converged)
    float thrv[16];
#pragma unroll
    for (int rf = 0; rf < 4; ++rf)
#pragma unroll
        for (int r = 0; r < 4; ++r)
            thrv[rf * 4 + r] = fmaf(2.4e-3f, __shfl(sax[rf], lk * 4 + r), 0.04f);

    if (lr == 0) {
#pragma unroll
        for (int t = 0; t < 16; ++t) {
            const int rloc = (t >> 2) * 16 + lk * 4 + (t & 3);
            codes[gr0 + rloc] = (float)i1[t];
            win[rloc] = i1[t];
            if (!(b2[t] - b1[t] >= thrv[t])) {   // small margin (and NaN) -> flag
                const int pos = atomicAdd(cnt, 1);
                list[pos] = (int)(gr0 + rloc);
            }
        }
    }
    __syncthreads();

    // ---- gather winner rows: 8 lanes per row, coalesced ----
#pragma unroll
    for (int i = 0; i < 8; ++i) {
        const int rloc = i * 8 + (lane >> 3);
        const int off = (lane & 7) * 16;
        const float* __restrict__ crow = cb + (long)win[rloc] * DDIM + off;
        float* __restrict__ qrow = quant + (gr0 + rloc) * DDIM + off;
#pragma unroll
        for (int q = 0; q < 4; ++q)
            *(float4*)(qrow + q * 4) = *(const float4*)(crow + q * 4);
    }
}

// ---------------- exact recheck v2: one wave per EIGHT flagged rows ----------
// lane = (row-slot gg = lane>>3, code-slot cs = lane&7); lane's codes are
// cs*128 + 0..127 (ascending). Exact serial-fma chain per (row,code), exact
// 4-chain xsq, dist = fmaf(-2,dot,xsq)+csq, strict-< ascending tie-breaks.
__launch_bounds__(256)
__global__ void recheck_kernel(const float* __restrict__ x, const float* __restrict__ cb,
                               const float* __restrict__ csq, float* __restrict__ quant,
                               float* __restrict__ codes, const int* __restrict__ cnt,
                               const int* __restrict__ list) {
    const int n = *cnt;
    if (n == 0) return;
    const int lane = threadIdx.x & 63;
    const int gg = lane >> 3;     // row slot 0..7
    const int cs = lane & 7;      // code slot 0..7
    const int wid = (blockIdx.x * 256 + threadIdx.x) >> 6;
    const int nw = (gridDim.x * 256) >> 6;

    for (int base = wid * 8; base < n; base += nw * 8) {
        const int li = base + gg;
        const int row = list[li < n ? li : (n - 1)];   // tail dups benign (exact)
        const float* __restrict__ xr = x + (long)row * DDIM;

        // exact xsq (4-chain)
        float s0 = 0.f, s1 = 0.f, s2 = 0.f, s3 = 0.f;
#pragma unroll
        for (int q = 0; q < 32; ++q) {
            const float4 u = *(const float4*)(xr + q * 4);
            s0 = fmaf(u.x, u.x, s0);
            s1 = fmaf(u.y, u.y, s1);
            s2 = fmaf(u.z, u.z, s2);
            s3 = fmaf(u.w, u.w, s3);
        }
        const float xsq = (s0 + s1) + (s2 + s3);

        float b = 3.4e38f;
        int bi = 0;
#pragma unroll 1
        for (int cg = 0; cg < 16; ++cg) {     // 8 codes per group
            const int k0 = cs * 128 + cg * 8;
            float accv[8];
#pragma unroll
            for (int c = 0; c < 8; ++c) accv[c] = 0.f;
#pragma unroll 1
            for (int dc = 0; dc < 8; ++dc) {  // 16 dims per chunk
                float xv[16];
#pragma unroll
                for (int q = 0; q < 4; ++q) {
                    const float4 u = *(const float4*)(xr + dc * 16 + q * 4);
                    xv[q * 4 + 0] = u.x; xv[q * 4 + 1] = u.y;
                    xv[q * 4 + 2] = u.z; xv[q * 4 + 3] = u.w;
                }
#pragma unroll
                for (int c = 0; c < 8; ++c) {
                    const float* __restrict__ cr = cb + (long)(k0 + c) * DDIM + dc * 16;
                    float a = accv[c];
#pragma unroll
                    for (int q = 0; q < 4; ++q) {
                        const float4 c4 = *(const float4*)(cr + q * 4);
                        a = fmaf(xv[q * 4 + 0], c4.x, a);
                        a = fmaf(xv[q * 4 + 1], c4.y, a);
                        a = fmaf(xv[q * 4 + 2], c4.z, a);
                        a = fmaf(xv[q * 4 + 3], c4.w, a);
                    }
                    accv[c] = a;
                }
            }
#pragma unroll
            for (int c = 0; c < 8; ++c) {
                const float dist = fmaf(-2.0f, accv[c], xsq) + csq[k0 + c];
                if (dist < b) { b = dist; bi = k0 + c; }
            }
        }

        // reduce across the 8 cs-lanes of this row (value, then index)
#pragma unroll
        for (int off = 1; off <= 4; off <<= 1) {
            const float ov = __shfl_xor(b, off);
            const int oi = __shfl_xor(bi, off);
            if (ov < b || (ov == b && oi < bi)) { b = ov; bi = oi; }
        }
        // all 8 lanes of the group now agree on bi
        if (cs == 0) codes[row] = (float)bi;
        const float* __restrict__ crow = cb + (long)bi * DDIM + cs * 16;
        float* __restrict__ qrow = quant + (long)row * DDIM + cs * 16;
#pragma unroll
        for (int q = 0; q < 4; ++q)
            *(float4*)(qrow + q * 4) = *(const float4*)(crow + q * 4);
    }
}

extern "C" void kernel_launch(void* const* d_in, const int* in_sizes, int n_in,
                              void* d_out, int out_size, void* d_ws, size_t ws_size,
                              hipStream_t stream) {
    const float* x  = (const float*)d_in[0];
    const float* cb = (const float*)d_in[1];
    const int B = in_sizes[0] / DDIM;  // 200000

    float* quant = (float*)d_out;
    float* codes = (float*)d_out + (size_t)B * DDIM;

    char* ws = (char*)d_ws;
    float* csq = (float*)ws;                         // 4 KB
    int*   cnt = (int*)(ws + 4096);                  // 4 B
    h8*    B2  = (h8*)(ws + 8192);                   // 256 KB
    int*   list = (int*)(ws + 8192 + 262144);        // 800 KB

    csq_kernel<<<(KCODES + 255) / 256, 256, 0, stream>>>(cb, csq, cnt);
    bprep_kernel<<<64, 256, 0, stream>>>(cb, B2);
    vq_mfma_kernel<<<B / 64, 64, 0, stream>>>(x, cb, B2, csq, quant, codes, cnt, list);
    recheck_kernel<<<2048, 256, 0, stream>>>(x, cb, csq, quant, codes, cnt, list);
}

// Round 6
// 1690.462 us; speedup vs baseline: 1.3978x; 1.3978x over previous
//
#include <hip/hip_runtime.h>

// VQ: B=200000 rows (D=128 fp32) vs K=1024 codes; out = [quant B*D | codes B] fp32.
//
// R8. R7 post-mortem: (1) recheck (1877us, VALUBusy 6%) was killed by
// lane-divergent code-row reads (64 cache lines per load instr -> L1
// serialization), NOT by bytes; (2) vq_mfma (~475us) is B-frag load-latency
// serialized per c16 (no prefetch) at 2 waves/SIMD (A-frags = 128 VGPR).
// Fixes:
//  * recheck v3 = R5's proven scalar-x + transposed-codebook machinery per
//    flagged row: x dims via s_load_dwordx2 (double-buffered, lgkmcnt AFTER
//    compute + sched_barrier, rule #18), codes via coalesced v2f loads from
//    cT[d][k]; v_pk_fma_f32 with SGPR broadcast. Exact serial-over-d fma
//    chain per (row,code) -- same association as the R6/R7-proven recheck.
//  * vq_mfma v2: 32 rows/wave (A-frags 64 VGPR -> 3 waves/SIMD,
//    launch_bounds(64,3)) + register double-buffered B-frag prefetch
//    (load c16+1 while MFMAing c16). Split/threshold/flag logic unchanged
//    (absmax-0.0-proven in R7).
// Numerics: unflagged rows provably match the exact chain (margin > rigorous
// bound thr = 2.4e-3*sax + 0.04); flagged rows recomputed with the exact
// chain + 4-chain xsq + fmaf(-2,dot,xsq)+csq + ascending tie-breaks.

typedef _Float16 f16;
typedef f16 h8 __attribute__((ext_vector_type(8)));
typedef float f4 __attribute__((ext_vector_type(4)));
typedef float v2f __attribute__((ext_vector_type(2)));
typedef int   v2i __attribute__((ext_vector_type(2)));

#define DDIM 128
#define KCODES 1024

// ---------------- csq (exact 4-chain) + zero flag counter --------------------
__global__ void csq_kernel(const float* __restrict__ cb, float* __restrict__ csq,
                           int* __restrict__ cnt) {
    if (blockIdx.x == 0 && threadIdx.x == 0) *cnt = 0;
    int k = blockIdx.x * blockDim.x + threadIdx.x;
    if (k >= KCODES) return;
    const float* __restrict__ c = cb + (long)k * DDIM;
    float s0 = 0.f, s1 = 0.f, s2 = 0.f, s3 = 0.f;
#pragma unroll
    for (int d = 0; d < DDIM; d += 4) {
        s0 = fmaf(c[d + 0], c[d + 0], s0);
        s1 = fmaf(c[d + 1], c[d + 1], s1);
        s2 = fmaf(c[d + 2], c[d + 2], s2);
        s3 = fmaf(c[d + 3], c[d + 3], s3);
    }
    csq[k] = (s0 + s1) + (s2 + s3);
}

// ---------------- pack Ch frag-linear (256 KB) -------------------------------
__global__ void bprep_kernel(const float* __restrict__ cb, h8* __restrict__ B2) {
    const int t = blockIdx.x * 256 + threadIdx.x;   // 0..16383
    const int tile = t >> 6;                        // 0..255
    const int lane = t & 63;
    const int c16 = tile >> 2, kf = tile & 3;
    const int col = c16 * 16 + (lane & 15);
    const int k0 = kf * 32 + (lane >> 4) * 8;
    const float* __restrict__ p = cb + (long)col * DDIM + k0;
    h8 out;
#pragma unroll
    for (int j = 0; j < 8; ++j) out[j] = (f16)p[j];
    B2[tile * 64 + lane] = out;
}

// ---------------- codebook transpose: cT[d][k] (512 KB) ----------------------
__global__ void ct_kernel(const float* __restrict__ cb, float* __restrict__ cT) {
    const int idx = blockIdx.x * 256 + threadIdx.x;  // 0..131071
    const int d = idx >> 10, k = idx & 1023;
    cT[idx] = cb[k * DDIM + d];
}

// ---------------- main MFMA kernel: 1 wave = 32 rows x 1024 codes ------------
__launch_bounds__(64, 3)
__global__ void vq_mfma_kernel(const float* __restrict__ x, const float* __restrict__ cb,
                               const h8* __restrict__ B2, const float* __restrict__ csq,
                               float* __restrict__ quant, float* __restrict__ codes,
                               int* __restrict__ cnt, int* __restrict__ list) {
    __shared__ int win[32];
    const int lane = threadIdx.x;
    const long gr0 = (long)blockIdx.x * 32;
    const int lr = lane & 15;     // A-row / B-col within a frag
    const int lk = lane >> 4;     // k-group

    // ---- A frags: hi = fp16(x), lo = fp16((x - hi)*2048); per-row sum|x| ----
    h8 ah[2][4], al[2][4];
    float sax[2];
#pragma unroll
    for (int rf = 0; rf < 2; ++rf) {
        float sx = 0.f;
#pragma unroll
        for (int kf = 0; kf < 4; ++kf) {
            const float* __restrict__ p =
                x + (gr0 + rf * 16 + lr) * DDIM + kf * 32 + lk * 8;
            const float4 u0 = *(const float4*)p;
            const float4 u1 = *(const float4*)(p + 4);
            const float xv[8] = {u0.x, u0.y, u0.z, u0.w, u1.x, u1.y, u1.z, u1.w};
#pragma unroll
            for (int j = 0; j < 8; ++j) {
                const float v = xv[j];
                const f16 h = (f16)v;
                ah[rf][kf][j] = h;
                al[rf][kf][j] = (f16)((v - (float)h) * 2048.f);
                sx += fabsf(v);
            }
        }
        sx += __shfl_xor(sx, 16);
        sx += __shfl_xor(sx, 32);
        sax[rf] = sx;
    }

    float b1[8], b2[8];
    int ic[8];
#pragma unroll
    for (int t = 0; t < 8; ++t) { b1[t] = 3.4e38f; b2[t] = 3.4e38f; ic[t] = 0; }

    const h8* __restrict__ bp = B2 + lane;

#define MLOAD(F, c16) \
    F##0 = bp[((c16) * 4 + 0) * 64]; F##1 = bp[((c16) * 4 + 1) * 64]; \
    F##2 = bp[((c16) * 4 + 2) * 64]; F##3 = bp[((c16) * 4 + 3) * 64];

#define MCOMP(F, c16) do { \
    const float cq = csq[(c16) * 16 + lr]; \
    _Pragma("unroll") \
    for (int rf = 0; rf < 2; ++rf) { \
        f4 hi = (f4){0.f, 0.f, 0.f, 0.f}; \
        f4 mid = (f4){0.f, 0.f, 0.f, 0.f}; \
        hi  = __builtin_amdgcn_mfma_f32_16x16x32_f16(ah[rf][0], F##0, hi, 0, 0, 0); \
        mid = __builtin_amdgcn_mfma_f32_16x16x32_f16(al[rf][0], F##0, mid, 0, 0, 0); \
        hi  = __builtin_amdgcn_mfma_f32_16x16x32_f16(ah[rf][1], F##1, hi, 0, 0, 0); \
        mid = __builtin_amdgcn_mfma_f32_16x16x32_f16(al[rf][1], F##1, mid, 0, 0, 0); \
        hi  = __builtin_amdgcn_mfma_f32_16x16x32_f16(ah[rf][2], F##2, hi, 0, 0, 0); \
        mid = __builtin_amdgcn_mfma_f32_16x16x32_f16(al[rf][2], F##2, mid, 0, 0, 0); \
        hi  = __builtin_amdgcn_mfma_f32_16x16x32_f16(ah[rf][3], F##3, hi, 0, 0, 0); \
        mid = __builtin_amdgcn_mfma_f32_16x16x32_f16(al[rf][3], F##3, mid, 0, 0, 0); \
        _Pragma("unroll") \
        for (int r = 0; r < 4; ++r) { \
            const float dot = fmaf(mid[r], 4.8828125e-4f, hi[r]); \
            const float s = fmaf(-2.0f, dot, cq); \
            const int t = rf * 4 + r; \
            b2[t] = fminf(fmaxf(s, b1[t]), b2[t]); \
            if (s < b1[t]) { b1[t] = s; ic[t] = (c16); } \
        } \
    } } while (0)

    h8 fA0, fA1, fA2, fA3, fB0, fB1, fB2, fB3;
    MLOAD(fA, 0)
#pragma unroll 1
    for (int c0 = 0; c0 < 64; c0 += 2) {
        MLOAD(fB, c0 + 1)
        MCOMP(fA, c0);
        if (c0 + 2 < 64) { MLOAD(fA, c0 + 2) }
        MCOMP(fB, c0 + 1);
    }
#undef MLOAD
#undef MCOMP

    // ---- full col index; reduce (b1,i1,b2) across the 16 lr-lanes ----
    int i1[8];
#pragma unroll
    for (int t = 0; t < 8; ++t) i1[t] = ic[t] * 16 + lr;
#pragma unroll
    for (int t = 0; t < 8; ++t) {
#pragma unroll
        for (int off = 1; off <= 8; off <<= 1) {
            const float ob1 = __shfl_xor(b1[t], off);
            const int   oi  = __shfl_xor(i1[t], off);
            const float ob2 = __shfl_xor(b2[t], off);
            const bool ow = (ob1 < b1[t]) || (ob1 == b1[t] && oi < i1[t]);
            const float nb2 = ow ? fminf(b1[t], ob2) : fminf(ob1, b2[t]);
            if (ow) { b1[t] = ob1; i1[t] = oi; }
            b2[t] = nb2;
        }
    }

    float thrv[8];
#pragma unroll
    for (int rf = 0; rf < 2; ++rf)
#pragma unroll
        for (int r = 0; r < 4; ++r)
            thrv[rf * 4 + r] = fmaf(2.4e-3f, __shfl(sax[rf], lk * 4 + r), 0.04f);

    if (lr == 0) {
#pragma unroll
        for (int t = 0; t < 8; ++t) {
            const int rloc = (t >> 2) * 16 + lk * 4 + (t & 3);
            codes[gr0 + rloc] = (float)i1[t];
            win[rloc] = i1[t];
            if (!(b2[t] - b1[t] >= thrv[t])) {
                const int pos = atomicAdd(cnt, 1);
                list[pos] = (int)(gr0 + rloc);
            }
        }
    }
    __syncthreads();

    // ---- gather winner rows: 8 lanes per row, coalesced ----
#pragma unroll
    for (int i = 0; i < 4; ++i) {
        const int rloc = i * 8 + (lane >> 3);
        const int off = (lane & 7) * 16;
        const float* __restrict__ crow = cb + (long)win[rloc] * DDIM + off;
        float* __restrict__ qrow = quant + (gr0 + rloc) * DDIM + off;
#pragma unroll
        for (int q = 0; q < 4; ++q)
            *(float4*)(qrow + q * 4) = *(const float4*)(crow + q * 4);
    }
}

// ---------------- exact recheck v3: 1 wave per flagged row -------------------
// x dims scalar (s_load_dwordx2 pairs, double-buffered); codes coalesced from
// cT[d][k] (lane owns k = t*128 + lane*2 + {0,1}, t=0..7). Exact serial-fma
// chain per (row,code) via PKL/PKH; exact 4-chain xsq; ascending tie-breaks.

#define PKL(a, xx, cc) \
    asm("v_pk_fma_f32 %0, %1, %2, %0 op_sel:[0,0,0] op_sel_hi:[0,1,1]" \
        : "+v"(a) : "s"(xx), "v"(cc))
#define PKH(a, xx, cc) \
    asm("v_pk_fma_f32 %0, %1, %2, %0 op_sel:[1,0,0] op_sel_hi:[1,1,1]" \
        : "+v"(a) : "s"(xx), "v"(cc))

#define DECLP(S) v2i xp##S##0, xp##S##1, xp##S##2, xp##S##3, \
                     xp##S##4, xp##S##5, xp##S##6, xp##S##7;

// 8 s_load_dwordx2: dim-pairs p=0..7 of a 16-dim chunk (consecutive, 8B apart)
#define ISSUEP(S, basep) do { const float* _xb = (basep); \
    asm volatile( \
        "s_load_dwordx2 %[a0], %[xb], 0x0\n\t" \
        "s_load_dwordx2 %[a1], %[xb], 0x8\n\t" \
        "s_load_dwordx2 %[a2], %[xb], 0x10\n\t" \
        "s_load_dwordx2 %[a3], %[xb], 0x18\n\t" \
        "s_load_dwordx2 %[a4], %[xb], 0x20\n\t" \
        "s_load_dwordx2 %[a5], %[xb], 0x28\n\t" \
        "s_load_dwordx2 %[a6], %[xb], 0x30\n\t" \
        "s_load_dwordx2 %[a7], %[xb], 0x38" \
        : [a0] "=s"(xp##S##0), [a1] "=s"(xp##S##1), \
          [a2] "=s"(xp##S##2), [a3] "=s"(xp##S##3), \
          [a4] "=s"(xp##S##4), [a5] "=s"(xp##S##5), \
          [a6] "=s"(xp##S##6), [a7] "=s"(xp##S##7) \
        : [xb] "s"(_xb)); } while (0)

// compute one dim-pair p of chunk: 8 v2f-pairs of codes at dim d and d+1
#define RPAIR(S, P, d) do { \
    const float* _c0 = cT + (d) * 1024 + lane * 2; \
    const float* _c1 = _c0 + 1024; \
    v2f u0 = *(const v2f*)(_c0);       v2f u1 = *(const v2f*)(_c0 + 128); \
    v2f u2 = *(const v2f*)(_c0 + 256); v2f u3 = *(const v2f*)(_c0 + 384); \
    v2f u4 = *(const v2f*)(_c0 + 512); v2f u5 = *(const v2f*)(_c0 + 640); \
    v2f u6 = *(const v2f*)(_c0 + 768); v2f u7 = *(const v2f*)(_c0 + 896); \
    PKL(acc0, xp##S##P, u0); PKL(acc1, xp##S##P, u1); \
    PKL(acc2, xp##S##P, u2); PKL(acc3, xp##S##P, u3); \
    PKL(acc4, xp##S##P, u4); PKL(acc5, xp##S##P, u5); \
    PKL(acc6, xp##S##P, u6); PKL(acc7, xp##S##P, u7); \
    v2f w0 = *(const v2f*)(_c1);       v2f w1 = *(const v2f*)(_c1 + 128); \
    v2f w2 = *(const v2f*)(_c1 + 256); v2f w3 = *(const v2f*)(_c1 + 384); \
    v2f w4 = *(const v2f*)(_c1 + 512); v2f w5 = *(const v2f*)(_c1 + 640); \
    v2f w6 = *(const v2f*)(_c1 + 768); v2f w7 = *(const v2f*)(_c1 + 896); \
    PKH(acc0, xp##S##P, w0); PKH(acc1, xp##S##P, w1); \
    PKH(acc2, xp##S##P, w2); PKH(acc3, xp##S##P, w3); \
    PKH(acc4, xp##S##P, w4); PKH(acc5, xp##S##P, w5); \
    PKH(acc6, xp##S##P, w6); PKH(acc7, xp##S##P, w7); } while (0)

#define RCHUNK(S, ch) do { \
    RPAIR(S, 0, (ch) * 16 + 0);  RPAIR(S, 1, (ch) * 16 + 2); \
    RPAIR(S, 2, (ch) * 16 + 4);  RPAIR(S, 3, (ch) * 16 + 6); \
    RPAIR(S, 4, (ch) * 16 + 8);  RPAIR(S, 5, (ch) * 16 + 10); \
    RPAIR(S, 6, (ch) * 16 + 12); RPAIR(S, 7, (ch) * 16 + 14); } while (0)

__launch_bounds__(256)
__global__ void recheck_kernel(const float* __restrict__ x, const float* __restrict__ cb,
                               const float* __restrict__ cT, const float* __restrict__ csq,
                               float* __restrict__ quant, float* __restrict__ codes,
                               const int* __restrict__ cnt, const int* __restrict__ list) {
    const int n = *cnt;
    if (n == 0) return;
    const int lane = threadIdx.x & 63;
    const int wid = (blockIdx.x * 256 + threadIdx.x) >> 6;
    const int nw = (gridDim.x * 256) >> 6;

    for (int it = wid; it < n; it += nw) {
        const int row = __builtin_amdgcn_readfirstlane(list[it]);
        const float* __restrict__ xr = x + (long)row * DDIM;

        // exact xsq (4-chain, broadcast loads)
        float s0 = 0.f, s1 = 0.f, s2 = 0.f, s3 = 0.f;
#pragma unroll
        for (int q = 0; q < 32; ++q) {
            const float4 u = *(const float4*)(xr + q * 4);
            s0 = fmaf(u.x, u.x, s0);
            s1 = fmaf(u.y, u.y, s1);
            s2 = fmaf(u.z, u.z, s2);
            s3 = fmaf(u.w, u.w, s3);
        }
        const float xsq = (s0 + s1) + (s2 + s3);

        v2f acc0 = (v2f){0.f, 0.f}, acc1 = (v2f){0.f, 0.f};
        v2f acc2 = (v2f){0.f, 0.f}, acc3 = (v2f){0.f, 0.f};
        v2f acc4 = (v2f){0.f, 0.f}, acc5 = (v2f){0.f, 0.f};
        v2f acc6 = (v2f){0.f, 0.f}, acc7 = (v2f){0.f, 0.f};

        DECLP(A) DECLP(B)
        ISSUEP(A, xr);
        asm volatile("s_waitcnt lgkmcnt(0)" ::: "memory");
        __builtin_amdgcn_sched_barrier(0);

#define RSTEP(CUR, NXT, ch) do { \
        const int nc = ((ch) < 7) ? ((ch) + 1) : 7; \
        ISSUEP(NXT, xr + nc * 16); \
        RCHUNK(CUR, ch); \
        asm volatile("s_waitcnt lgkmcnt(0)" ::: "memory"); \
        __builtin_amdgcn_sched_barrier(0); \
} while (0)
#pragma unroll 1
        for (int c = 0; c < 8; c += 2) {
            RSTEP(A, B, c);
            RSTEP(B, A, c + 1);
        }
#undef RSTEP

        // dists + lane-local argmin (k ascending: t asc, half asc)
        float b = 3.4e38f;
        int bi = 0;
        const v2f accs[8] = {acc0, acc1, acc2, acc3, acc4, acc5, acc6, acc7};
#pragma unroll
        for (int t = 0; t < 8; ++t) {
            const int k0 = t * 128 + lane * 2;
#pragma unroll
            for (int h = 0; h < 2; ++h) {
                const float dist = fmaf(-2.0f, accs[t][h], xsq) + csq[k0 + h];
                if (dist < b) { b = dist; bi = k0 + h; }
            }
        }
        // 64-lane butterfly (value, then index)
#pragma unroll
        for (int off = 32; off >= 1; off >>= 1) {
            const float ov = __shfl_xor(b, off);
            const int oi = __shfl_xor(bi, off);
            if (ov < b || (ov == b && oi < bi)) { b = ov; bi = oi; }
        }
        if (lane == 0) codes[row] = (float)bi;
        const float* __restrict__ crow = cb + (long)bi * DDIM + lane * 2;
        float* __restrict__ qrow = quant + (long)row * DDIM + lane * 2;
        qrow[0] = crow[0];
        qrow[1] = crow[1];
    }
}

extern "C" void kernel_launch(void* const* d_in, const int* in_sizes, int n_in,
                              void* d_out, int out_size, void* d_ws, size_t ws_size,
                              hipStream_t stream) {
    const float* x  = (const float*)d_in[0];
    const float* cb = (const float*)d_in[1];
    const int B = in_sizes[0] / DDIM;  // 200000

    float* quant = (float*)d_out;
    float* codes = (float*)d_out + (size_t)B * DDIM;

    char* ws = (char*)d_ws;
    float* csq = (float*)ws;                         // 4 KB
    int*   cnt = (int*)(ws + 4096);                  // 4 B
    h8*    B2  = (h8*)(ws + 8192);                   // 256 KB
    float* cT  = (float*)(ws + 8192 + 262144);       // 512 KB
    int*   list = (int*)(ws + 8192 + 262144 + 524288);  // 800 KB

    csq_kernel<<<(KCODES + 255) / 256, 256, 0, stream>>>(cb, csq, cnt);
    bprep_kernel<<<64, 256, 0, stream>>>(cb, B2);
    ct_kernel<<<512, 256, 0, stream>>>(cb, cT);
    vq_mfma_kernel<<<B / 32, 64, 0, stream>>>(x, cb, B2, csq, quant, codes, cnt, list);
    recheck_kernel<<<1024, 256, 0, stream>>>(x, cb, cT, csq, quant, codes, cnt, list);
}